// Round 11
// baseline (105.008 us; speedup 1.0000x reference)
//
#include <hip/hip_runtime.h>
#include <math.h>

// NetVLAD on MI355X via bf16 hi/lo-split MFMA (3-product emulated fp32).
// N=128 images, C=256 channels, K=64 clusters, P=1024 pixels.
// Block = (image, eighth); decode n = blockIdx&127, e = blockIdx>>7 so the
// 8 siblings of an image share one XCD (round-robin idx%8 = n%8) -> their
// atomicAdds accumulate in that XCD's L2 and flush once.
// 4 blocks/CU (LDS 38.4KB), 1024 blocks = exactly one resident round.
// Pass 1: slab [128 p][18] hi/lo dbuf, 2-ahead register prefetch (gA/gB);
//   wave = 32 pixels x all 64 clusters; W-frags pre-split in ws (prep kernel);
//   softmax fully in-register, a written once as packed split.
// Pass 2: slab [2][32 c][68] hi/lo aliased into abuf region; wave = 16
//   clusters; a' = a*rn resplit once; asum via ones-MFMA; coalesced atomics.
// MFMA 16x16x32 bf16: A row=l15,k=8*lg4+j; B col=l15,same k;
//                     C col=l15,row=4*lg4+reg  (verified R2-R10)

#define EPSF 1e-12f

typedef __attribute__((ext_vector_type(8))) __bf16 bf16x8;
typedef __attribute__((ext_vector_type(4))) float f32x4;
typedef __attribute__((ext_vector_type(4))) unsigned int u32x4;

#define MFMA(a, b, c) __builtin_amdgcn_mfma_f32_16x16x32_bf16((a), (b), (c), 0, 0, 0)

__device__ __forceinline__ bf16x8 as_bf(u32x4 v) { return __builtin_bit_cast(bf16x8, v); }

// f32 -> packed (hi_bf16 << 16) | lo_bf16  (truncation split, err ~2^-16|x|)
__device__ __forceinline__ unsigned packsplit(float x) {
    const unsigned u  = __float_as_uint(x);
    const unsigned hi = u & 0xFFFF0000u;
    const float lof   = x - __uint_as_float(hi);
    return hi | (__float_as_uint(lof) >> 16);
}

struct u32pair { unsigned h, l; };

// two f32 -> hi-pair u32 and lo-pair u32 (bf16x2 each, elem order f0,f1)
__device__ __forceinline__ u32pair splitpair(float f0, float f1) {
    const unsigned u0 = __float_as_uint(f0), u1 = __float_as_uint(f1);
    u32pair r;
    r.h = __builtin_amdgcn_perm(u1, u0, 0x07060302u);
    const float l0 = f0 - __uint_as_float(u0 & 0xFFFF0000u);
    const float l1 = f1 - __uint_as_float(u1 & 0xFFFF0000u);
    r.l = __builtin_amdgcn_perm(__float_as_uint(l1), __float_as_uint(l0), 0x07060302u);
    return r;
}

// 8 packed u32 (two aligned quads) -> (hi,lo) MFMA operand pair
__device__ __forceinline__ void unpack2q(const u32x4 q0, const u32x4 q1,
                                         u32x4& hi, u32x4& lo) {
    hi[0] = __builtin_amdgcn_perm(q0[1], q0[0], 0x07060302u);
    lo[0] = __builtin_amdgcn_perm(q0[1], q0[0], 0x05040100u);
    hi[1] = __builtin_amdgcn_perm(q0[3], q0[2], 0x07060302u);
    lo[1] = __builtin_amdgcn_perm(q0[3], q0[2], 0x05040100u);
    hi[2] = __builtin_amdgcn_perm(q1[1], q1[0], 0x07060302u);
    lo[2] = __builtin_amdgcn_perm(q1[1], q1[0], 0x05040100u);
    hi[3] = __builtin_amdgcn_perm(q1[3], q1[2], 0x07060302u);
    lo[3] = __builtin_amdgcn_perm(q1[3], q1[2], 0x05040100u);
}

__device__ __forceinline__ void split8v(const float* xv, u32x4& hi, u32x4& lo) {
    #pragma unroll
    for (int w2 = 0; w2 < 4; ++w2) {
        const u32pair r = splitpair(xv[2*w2], xv[2*w2+1]);
        hi[w2] = r.h;
        lo[w2] = r.l;
    }
}

// ---- prep: split W into MFMA-A-fragment-ordered hi/lo arrays in ws.
// idx = mt*512 + s*64 + l : lane l of fragment (k-tile mt, slab s).
__global__ void split_w_kernel(const float* __restrict__ wmat,
                               unsigned* __restrict__ whiG,
                               unsigned* __restrict__ wloG) {
    const int idx = blockIdx.x * 256 + threadIdx.x;   // 2048 total
    const int mt = idx >> 9, s = (idx >> 6) & 7, l = idx & 63;
    const int k = mt * 16 + (l & 15);
    const int cb = s * 32 + 8 * (l >> 4);
    const float* wr = wmat + k * 256 + cb;
    const float4 f0 = *(const float4*)wr;
    const float4 f1 = *(const float4*)(wr + 4);
    const float xv[8] = {f0.x, f0.y, f0.z, f0.w, f1.x, f1.y, f1.z, f1.w};
    u32x4 hi, lo; split8v(xv, hi, lo);
    *(u32x4*)(whiG + idx * 4) = hi;
    *(u32x4*)(wloG + idx * 4) = lo;
}

__global__ __launch_bounds__(256, 4) void netvlad_mfma(
    const float* __restrict__ x,
    const unsigned* __restrict__ whiG, const unsigned* __restrict__ wloG,
    const float* __restrict__ bias, float* __restrict__ out,
    float* __restrict__ asum_g) {

    // phase-disjoint union region (36KB):
    //  phase 1: p1hi [2][128][18] @0..4607, p1lo @4608..9215
    //  phase 2: abuf [64][132] u32 @0..8447  (packed-split a)
    //  phase 3: p2hi [2][32][68]  @0..4351, p2lo @4352..8703
    __shared__ __align__(16) unsigned smem[9216];
    __shared__ __align__(16) float rn_lds[128];
    __shared__ __align__(16) float sspart[256];
    unsigned* const p1hi = smem;
    unsigned* const p1lo = smem + 4608;
    unsigned* const abuf = smem;
    unsigned* const p2hi = smem;
    unsigned* const p2lo = smem + 4352;

    const int t = threadIdx.x;
    const int w = t >> 6, l = t & 63;
    const int l15 = l & 15, lg4 = l >> 4;
    const int n = blockIdx.x & 127, e = blockIdx.x >> 7;   // XCD-local siblings
    const size_t ximg = (size_t)n * 256 * 1024;
    const int p0 = e * 128;
    const int k0 = w * 16;                 // pass-2: wave's 16-cluster tile
    const int cs = lg4 * 8;                // contraction slice base in K-step

    // ---- pass-1 staging: thread owns (pixel pp, 16-channel half) per slab
    const int pp = t & 127, half = t >> 7;
    const float* xg1 = x + ximg + (size_t)(half * 16) * 1024 + p0 + pp;
    unsigned* const w1hi = p1hi + pp * 18 + half * 8;
    unsigned* const w1lo = p1lo + pp * 18 + half * 8;
    float gA[16], gB[16];
    float ssacc = 0.f;

    #define P1_LOAD(gv_, s_) { _Pragma("unroll")                              \
        for (int i = 0; i < 16; ++i)                                          \
            gv_[i] = xg1[(size_t)((s_) * 32 + i) * 1024]; }
    #define P1_WRITE(gv_, b_) {                                               \
        u32x4 vh0, vl0, vh1, vl1;                                             \
        _Pragma("unroll")                                                     \
        for (int j = 0; j < 4; ++j) {                                         \
            const u32pair r0 = splitpair(gv_[2*j],   gv_[2*j+1]);             \
            const u32pair r1 = splitpair(gv_[8+2*j], gv_[8+2*j+1]);           \
            vh0[j] = r0.h; vl0[j] = r0.l;                                     \
            vh1[j] = r1.h; vl1[j] = r1.l;                                     \
        }                                                                     \
        _Pragma("unroll")                                                     \
        for (int i = 0; i < 16; ++i) ssacc = fmaf(gv_[i], gv_[i], ssacc);     \
        *(u32x4*)(w1hi + (b_) * 2304)     = vh0;                              \
        *(u32x4*)(w1hi + (b_) * 2304 + 4) = vh1;                              \
        *(u32x4*)(w1lo + (b_) * 2304)     = vl0;                              \
        *(u32x4*)(w1lo + (b_) * 2304 + 4) = vl1; }

    // ================= PASS 1: logits (wave = 32 pixels x all 64 k) ========
    f32x4 acc1[4][2];                      // [mt][ntl]; k=mt*16+4lg4+r, p=(2w+ntl)*16+l15
    #pragma unroll
    for (int i = 0; i < 4; ++i) {
        acc1[i][0] = f32x4{0.f, 0.f, 0.f, 0.f};
        acc1[i][1] = f32x4{0.f, 0.f, 0.f, 0.f};
    }

    P1_LOAD(gA, 0);
    P1_LOAD(gB, 1);
    P1_WRITE(gA, 0);                       // slab 0 -> buffer 0; gA free
    #pragma unroll
    for (int s = 0; s < 8; ++s) {
        // 2-ahead: load slab s+2 into the register buffer freed last iter
        if (s < 6) {
            if ((s & 1) == 0) { P1_LOAD(gA, s + 2); }
            else              { P1_LOAD(gB, s + 2); }
        }
        __syncthreads();                   // slab s visible; dbuf safe
        const unsigned* shi = p1hi + (s & 1) * 2304;
        const unsigned* slo = p1lo + (s & 1) * 2304;
        // W A-frags for this slab (identical addrs across waves -> L1-hot)
        u32x4 wh[4], wl[4];
        #pragma unroll
        for (int mt = 0; mt < 4; ++mt) {
            const int fo = ((mt * 8 + s) * 64 + l) * 4;
            wh[mt] = *(const u32x4*)(whiG + fo);
            wl[mt] = *(const u32x4*)(wloG + fo);
        }
        // B-frags: only the wave's own 2 pixel-tiles
        u32x4 bhi[2], blo[2];
        #pragma unroll
        for (int ntl = 0; ntl < 2; ++ntl) {
            const int ro = ((2 * w + ntl) * 16 + l15) * 18 + lg4 * 4;
            bhi[ntl] = *(const u32x4*)(shi + ro);
            blo[ntl] = *(const u32x4*)(slo + ro);
        }
        #pragma unroll
        for (int mt = 0; mt < 4; ++mt) {
            #pragma unroll
            for (int ntl = 0; ntl < 2; ++ntl) {
                acc1[mt][ntl] = MFMA(as_bf(wh[mt]), as_bf(bhi[ntl]), acc1[mt][ntl]);
                acc1[mt][ntl] = MFMA(as_bf(wh[mt]), as_bf(blo[ntl]), acc1[mt][ntl]);
                acc1[mt][ntl] = MFMA(as_bf(wl[mt]), as_bf(bhi[ntl]), acc1[mt][ntl]);
            }
        }
        // write slab s+1 (loaded one iteration ago -> latency fully hidden)
        if (s < 7) {
            if ((s & 1) == 0) { P1_WRITE(gB, 1); }
            else              { P1_WRITE(gA, 0); }
        }
    }
    sspart[t] = ssacc;

    // bias into regs: biasv[mt][r] = bias[mt*16+4lg4+r]
    f32x4 biasv[4];
    #pragma unroll
    for (int mt = 0; mt < 4; ++mt)
        biasv[mt] = *(const f32x4*)(bias + mt * 16 + 4 * lg4);

    // ---- pass-2 staging ids; issue slab-0 loads early (hide under softmax)
    const int r2 = t >> 4;                 // 0..15 (rows r2 and r2+16 per slab)
    const int pq8 = (t & 15) * 8;
    const float* xg2 = x + ximg + (size_t)r2 * 1024 + p0 + pq8;
    unsigned* const w2hi = p2hi + r2 * 68 + (pq8 >> 1);
    unsigned* const w2lo = p2lo + r2 * 68 + (pq8 >> 1);
    float4 g2[4];
    #define P2_LOAD(s_) { _Pragma("unroll")                                   \
        for (int i = 0; i < 2; ++i) {                                         \
            g2[i*2]   = *(const float4*)(xg2 + (size_t)((s_)*32 + 16*i)*1024);    \
            g2[i*2+1] = *(const float4*)(xg2 + (size_t)((s_)*32 + 16*i)*1024 + 4);\
        } }
    #define P2_WRITE(b_) { _Pragma("unroll")                                  \
        for (int i = 0; i < 2; ++i) {                                         \
            u32x4 vh, vl;                                                     \
            const u32pair ra = splitpair(g2[i*2].x,   g2[i*2].y);             \
            const u32pair rb = splitpair(g2[i*2].z,   g2[i*2].w);             \
            const u32pair rc = splitpair(g2[i*2+1].x, g2[i*2+1].y);           \
            const u32pair rd = splitpair(g2[i*2+1].z, g2[i*2+1].w);           \
            vh[0] = ra.h; vl[0] = ra.l;                                       \
            vh[1] = rb.h; vl[1] = rb.l;                                       \
            vh[2] = rc.h; vl[2] = rc.l;                                       \
            vh[3] = rd.h; vl[3] = rd.l;                                       \
            *(u32x4*)(w2hi + (b_) * 2176 + i * 1088) = vh;                    \
            *(u32x4*)(w2lo + (b_) * 2176 + i * 1088) = vl; } }
    P2_LOAD(0);
    __syncthreads();                       // pass-1 LDS reads done; sspart visible

    // ---- softmax fully in-register; rn computed here; packed a written
    #pragma unroll
    for (int ntl = 0; ntl < 2; ++ntl) {
        const int p = (2 * w + ntl) * 16 + l15;
        const float rn = 1.f / fmaxf(sqrtf(sspart[p] + sspart[p + 128]), EPSF);
        if (lg4 == 0) rn_lds[p] = rn;
        float lgv[16];
        #pragma unroll
        for (int mt = 0; mt < 4; ++mt)
            #pragma unroll
            for (int r = 0; r < 4; ++r)
                lgv[mt * 4 + r] = fmaf(acc1[mt][ntl][r], rn, biasv[mt][r]);
        float mx = lgv[0];
        #pragma unroll
        for (int i = 1; i < 16; ++i) mx = fmaxf(mx, lgv[i]);
        mx = fmaxf(mx, __shfl_xor(mx, 16));
        mx = fmaxf(mx, __shfl_xor(mx, 32));
        float den = 0.f;
        #pragma unroll
        for (int i = 0; i < 16; ++i) { lgv[i] = __expf(lgv[i] - mx); den += lgv[i]; }
        den += __shfl_xor(den, 16);
        den += __shfl_xor(den, 32);
        const float inv = 1.f / den;
        #pragma unroll
        for (int mt = 0; mt < 4; ++mt)
            #pragma unroll
            for (int r = 0; r < 4; ++r)
                abuf[(mt * 16 + 4 * lg4 + r) * 132 + p] =
                    packsplit(lgv[mt * 4 + r] * inv);
    }
    __syncthreads();                       // packed a + rn_lds visible

    // ---- A-frags for pass 2: raw a (asum) + a*rn resplit; held for all slabs
    u32x4 aphi[4], aplo[4];
    f32x4 asum_acc = f32x4{0.f, 0.f, 0.f, 0.f};
    const u32x4 ONES = {0x3F803F80u, 0x3F803F80u, 0x3F803F80u, 0x3F803F80u};
    #pragma unroll
    for (int ks = 0; ks < 4; ++ks) {
        const unsigned* ap = abuf + (k0 + l15) * 132 + ks * 32 + cs;
        const u32x4 pa = *(const u32x4*)ap;
        const u32x4 pb = *(const u32x4*)(ap + 4);
        u32x4 ahi, alo; unpack2q(pa, pb, ahi, alo);
        asum_acc = MFMA(as_bf(ahi), as_bf(ONES), asum_acc);
        asum_acc = MFMA(as_bf(alo), as_bf(ONES), asum_acc);
        // a' = a*rn, resplit once; reused by all 16 c-tiles
        const float* rp = rn_lds + ks * 32 + cs;
        const unsigned paw[8] = {pa[0],pa[1],pa[2],pa[3],pb[0],pb[1],pb[2],pb[3]};
        float av[8];
        #pragma unroll
        for (int j = 0; j < 8; ++j) {
            const float afv = __uint_as_float(paw[j] & 0xFFFF0000u)
                            + __uint_as_float(paw[j] << 16);
            av[j] = afv * rp[j];
        }
        split8v(av, aphi[ks], aplo[ks]);
    }
    __syncthreads();                       // abuf reads done -> p2 alias safe

    P2_WRITE(0);                           // slab 0

    // ================= PASS 2: agg[k][c] += a' @ x^T =================
    float* op = out + (size_t)n * 16384;
    #pragma unroll
    for (int s2 = 0; s2 < 8; ++s2) {
        if (s2 < 7) P2_LOAD(s2 + 1);
        __syncthreads();                   // slab s2 visible; dbuf safe
        const unsigned* shi = p2hi + (s2 & 1) * 2176;
        const unsigned* slo = p2lo + (s2 & 1) * 2176;
        f32x4 a2[2];
        #pragma unroll
        for (int ntl = 0; ntl < 2; ++ntl) {
            a2[ntl] = f32x4{0.f, 0.f, 0.f, 0.f};
            #pragma unroll
            for (int ks = 0; ks < 4; ++ks) {
                const int ro = (ntl * 16 + l15) * 68 + ks * 16 + lg4 * 4;
                const u32x4 xhi = *(const u32x4*)(shi + ro);
                const u32x4 xlo = *(const u32x4*)(slo + ro);
                a2[ntl] = MFMA(as_bf(aphi[ks]), as_bf(xhi), a2[ntl]);
                a2[ntl] = MFMA(as_bf(aphi[ks]), as_bf(xlo), a2[ntl]);
                a2[ntl] = MFMA(as_bf(aplo[ks]), as_bf(xhi), a2[ntl]);
            }
        }
        if (s2 < 7) P2_WRITE((s2 + 1) & 1);    // LDS write before atomics
        #pragma unroll
        for (int ntl = 0; ntl < 2; ++ntl) {
            const int c = s2 * 32 + ntl * 16 + l15;
            #pragma unroll
            for (int r = 0; r < 4; ++r)
                atomicAdd(&op[(k0 + lg4 * 4 + r) * 256 + c], a2[ntl][r]);
        }
    }
    if (l15 == 0) {
        #pragma unroll
        for (int r = 0; r < 4; ++r)
            atomicAdd(&asum_g[n * 64 + k0 + lg4 * 4 + r], asum_acc[r]);
    }
}

__global__ __launch_bounds__(256) void netvlad_epi(
    float* __restrict__ out, const float* __restrict__ asum_g,
    const float* __restrict__ cent) {
    __shared__ float wred[4];
    __shared__ float gs_sh;
    const int n = blockIdx.x;
    const int t = threadIdx.x;
    const int k = t >> 2;          // 4 threads per cluster row
    const int q = t & 3;
    float* op = out + (size_t)n * 16384 + k * 256 + q * 64;
    const float* cp = cent + k * 256 + q * 64;
    const float as = asum_g[n * 64 + k];

    float v[64];
    float ss = 0.f;
    #pragma unroll
    for (int i = 0; i < 64; i += 4) {
        const float4 av = *(const float4*)&op[i];
        const float4 cv = *(const float4*)&cp[i];
        v[i+0] = fmaf(-as, cv.x, av.x);
        v[i+1] = fmaf(-as, cv.y, av.y);
        v[i+2] = fmaf(-as, cv.z, av.z);
        v[i+3] = fmaf(-as, cv.w, av.w);
        ss = fmaf(v[i+0], v[i+0], ss);
        ss = fmaf(v[i+1], v[i+1], ss);
        ss = fmaf(v[i+2], v[i+2], ss);
        ss = fmaf(v[i+3], v[i+3], ss);
    }
    ss += __shfl_xor(ss, 1);
    ss += __shfl_xor(ss, 2);
    const float iscale = 1.f / fmaxf(sqrtf(ss), EPSF);

    float gsum = (q == 0) ? ss * iscale * iscale : 0.f;
    #pragma unroll
    for (int off = 4; off < 64; off <<= 1) gsum += __shfl_xor(gsum, off);
    if ((t & 63) == 0) wred[t >> 6] = gsum;
    __syncthreads();
    if (t == 0) {
        const float tot = wred[0] + wred[1] + wred[2] + wred[3];
        gs_sh = 1.f / fmaxf(sqrtf(tot), EPSF);
    }
    __syncthreads();
    const float fs = iscale * gs_sh;
    #pragma unroll
    for (int i = 0; i < 64; i += 4) {
        float4 w4;
        w4.x = v[i+0] * fs; w4.y = v[i+1] * fs;
        w4.z = v[i+2] * fs; w4.w = v[i+3] * fs;
        *(float4*)&op[i] = w4;
    }
}

extern "C" void kernel_launch(void* const* d_in, const int* in_sizes, int n_in,
                              void* d_out, int out_size, void* d_ws, size_t ws_size,
                              hipStream_t stream) {
    (void)in_sizes; (void)n_in; (void)ws_size;
    const float* x    = (const float*)d_in[0];
    const float* wmat = (const float*)d_in[1];
    const float* b    = (const float*)d_in[2];
    const float* cent = (const float*)d_in[3];
    float* out = (float*)d_out;
    unsigned* whiG = (unsigned*)d_ws;              // 8192 u32
    unsigned* wloG = whiG + 8192;                  // 8192 u32
    float* asum_g  = (float*)(whiG + 16384);       // 8192 f32

    hipMemsetAsync(d_out, 0, (size_t)out_size * sizeof(float), stream);
    hipMemsetAsync(asum_g, 0, 128 * 64 * sizeof(float), stream);
    split_w_kernel<<<8, 256, 0, stream>>>(wmat, whiG, wloG);
    netvlad_mfma<<<1024, 256, 0, stream>>>(x, whiG, wloG, b, out, asum_g);
    netvlad_epi<<<128, 256, 0, stream>>>(out, asum_g, cent);
}

// Round 12
// 100.187 us; speedup vs baseline: 1.0481x; 1.0481x over previous
//
#include <hip/hip_runtime.h>
#include <math.h>

// NetVLAD on MI355X via bf16 hi/lo-split MFMA (3-product emulated fp32).
// N=128 images, C=256 channels, K=64 clusters, P=1024 pixels.
// Block = (image, eighth): n = blockIdx&127, e = blockIdx>>7; 256 thr, 4 waves.
// PASS 1 (R12): LDS-FREE, BARRIER-FREE. Wave = 32 pixels x all 64 clusters.
//   B-frags read directly from global (64B segments, zero cross-wave
//   redundancy), split in-register; W-frags pre-split in ws (prep kernel);
//   ss via lane partials + shfl_xor; softmax fully in-register.
// PASS 2 (unchanged R9-R11): a packed in abuf; a' = a*rn resplit once/wave;
//   x re-staged [c][p] hi/lo dbuf slabs (b128, bank-padded); asum via
//   ones-MFMA; coalesced atomics.
// Barriers: 10 total (was 19). LDS 35KB -> 4 blocks/CU.
// MFMA 16x16x32 bf16: A row=l15,k=8*lg4+j; B col=l15,same k;
//                     C col=l15,row=4*lg4+reg  (verified R2-R11)

#define EPSF 1e-12f

typedef __attribute__((ext_vector_type(8))) __bf16 bf16x8;
typedef __attribute__((ext_vector_type(4))) float f32x4;
typedef __attribute__((ext_vector_type(4))) unsigned int u32x4;

#define MFMA(a, b, c) __builtin_amdgcn_mfma_f32_16x16x32_bf16((a), (b), (c), 0, 0, 0)

__device__ __forceinline__ bf16x8 as_bf(u32x4 v) { return __builtin_bit_cast(bf16x8, v); }

// f32 -> packed (hi_bf16 << 16) | lo_bf16  (truncation split, err ~2^-16|x|)
__device__ __forceinline__ unsigned packsplit(float x) {
    const unsigned u  = __float_as_uint(x);
    const unsigned hi = u & 0xFFFF0000u;
    const float lof   = x - __uint_as_float(hi);
    return hi | (__float_as_uint(lof) >> 16);
}

struct u32pair { unsigned h, l; };

// two f32 -> hi-pair u32 and lo-pair u32 (bf16x2 each, elem order f0,f1)
__device__ __forceinline__ u32pair splitpair(float f0, float f1) {
    const unsigned u0 = __float_as_uint(f0), u1 = __float_as_uint(f1);
    u32pair r;
    r.h = __builtin_amdgcn_perm(u1, u0, 0x07060302u);
    const float l0 = f0 - __uint_as_float(u0 & 0xFFFF0000u);
    const float l1 = f1 - __uint_as_float(u1 & 0xFFFF0000u);
    r.l = __builtin_amdgcn_perm(__float_as_uint(l1), __float_as_uint(l0), 0x07060302u);
    return r;
}

// 8 packed u32 (two aligned quads) -> (hi,lo) MFMA operand pair
__device__ __forceinline__ void unpack2q(const u32x4 q0, const u32x4 q1,
                                         u32x4& hi, u32x4& lo) {
    hi[0] = __builtin_amdgcn_perm(q0[1], q0[0], 0x07060302u);
    lo[0] = __builtin_amdgcn_perm(q0[1], q0[0], 0x05040100u);
    hi[1] = __builtin_amdgcn_perm(q0[3], q0[2], 0x07060302u);
    lo[1] = __builtin_amdgcn_perm(q0[3], q0[2], 0x05040100u);
    hi[2] = __builtin_amdgcn_perm(q1[1], q1[0], 0x07060302u);
    lo[2] = __builtin_amdgcn_perm(q1[1], q1[0], 0x05040100u);
    hi[3] = __builtin_amdgcn_perm(q1[3], q1[2], 0x07060302u);
    lo[3] = __builtin_amdgcn_perm(q1[3], q1[2], 0x05040100u);
}

__device__ __forceinline__ void split8v(const float* xv, u32x4& hi, u32x4& lo) {
    #pragma unroll
    for (int w2 = 0; w2 < 4; ++w2) {
        const u32pair r = splitpair(xv[2*w2], xv[2*w2+1]);
        hi[w2] = r.h;
        lo[w2] = r.l;
    }
}

// ---- prep: split W into MFMA-A-fragment-ordered hi/lo arrays in ws.
// idx = mt*512 + s*64 + l : lane l of fragment (k-tile mt, slab s).
__global__ void split_w_kernel(const float* __restrict__ wmat,
                               unsigned* __restrict__ whiG,
                               unsigned* __restrict__ wloG) {
    const int idx = blockIdx.x * 256 + threadIdx.x;   // 2048 total
    const int mt = idx >> 9, s = (idx >> 6) & 7, l = idx & 63;
    const int k = mt * 16 + (l & 15);
    const int cb = s * 32 + 8 * (l >> 4);
    const float* wr = wmat + k * 256 + cb;
    const float4 f0 = *(const float4*)wr;
    const float4 f1 = *(const float4*)(wr + 4);
    const float xv[8] = {f0.x, f0.y, f0.z, f0.w, f1.x, f1.y, f1.z, f1.w};
    u32x4 hi, lo; split8v(xv, hi, lo);
    *(u32x4*)(whiG + idx * 4) = hi;
    *(u32x4*)(wloG + idx * 4) = lo;
}

__global__ __launch_bounds__(256, 4) void netvlad_mfma(
    const float* __restrict__ x,
    const unsigned* __restrict__ whiG, const unsigned* __restrict__ wloG,
    const float* __restrict__ bias, float* __restrict__ out,
    float* __restrict__ asum_g) {

    // phase-disjoint union region (34.8KB):
    //  phase A: abuf [64][132] u32 @0..8447  (packed-split a)
    //  phase B: p2hi [2][32][68] @0..4351, p2lo @4352..8703
    __shared__ __align__(16) unsigned smem[8704];
    __shared__ __align__(16) float rn_lds[128];
    unsigned* const abuf = smem;
    unsigned* const p2hi = smem;
    unsigned* const p2lo = smem + 4352;

    const int t = threadIdx.x;
    const int w = t >> 6, l = t & 63;
    const int l15 = l & 15, lg4 = l >> 4;
    const int n = blockIdx.x & 127, e = blockIdx.x >> 7;
    const size_t ximg = (size_t)n * 256 * 1024;
    const int p0 = e * 128;
    const int k0 = w * 16;                 // pass-2: wave's 16-cluster tile
    const int cs = lg4 * 8;                // contraction slice base in K-step

    // ================= PASS 1: logits, LDS-free & barrier-free =============
    // wave = 32 pixels (2 tiles of 16) x all 64 clusters.
    f32x4 acc1[4][2];                      // [mt][ntl]
    #pragma unroll
    for (int i = 0; i < 4; ++i) {
        acc1[i][0] = f32x4{0.f, 0.f, 0.f, 0.f};
        acc1[i][1] = f32x4{0.f, 0.f, 0.f, 0.f};
    }
    float ssa[2] = {0.f, 0.f};             // per-(lg4-slice) sum of x^2

    #pragma unroll
    for (int s = 0; s < 8; ++s) {
        // W A-frags for this slab (same addrs across waves -> L1-hot)
        u32x4 wh[4], wl[4];
        #pragma unroll
        for (int mt = 0; mt < 4; ++mt) {
            const int fo = ((mt * 8 + s) * 64 + l) * 4;
            wh[mt] = *(const u32x4*)(whiG + fo);
            wl[mt] = *(const u32x4*)(wloG + fo);
        }
        #pragma unroll
        for (int ntl = 0; ntl < 2; ++ntl) {
            // B frag direct from global: x[c = s*32+cs+j][p], 8 strided dwords,
            // 64B segments across l15, disjoint across waves.
            const float* bp = x + ximg + (size_t)(s * 32 + cs) * 1024
                              + p0 + (2 * w + ntl) * 16 + l15;
            float xv[8];
            #pragma unroll
            for (int j = 0; j < 8; ++j) xv[j] = bp[(size_t)j * 1024];
            #pragma unroll
            for (int j = 0; j < 8; ++j) ssa[ntl] = fmaf(xv[j], xv[j], ssa[ntl]);
            u32x4 bhi, blo; split8v(xv, bhi, blo);
            #pragma unroll
            for (int mt = 0; mt < 4; ++mt) {
                acc1[mt][ntl] = MFMA(as_bf(wh[mt]), as_bf(bhi), acc1[mt][ntl]);
                acc1[mt][ntl] = MFMA(as_bf(wh[mt]), as_bf(blo), acc1[mt][ntl]);
                acc1[mt][ntl] = MFMA(as_bf(wl[mt]), as_bf(bhi), acc1[mt][ntl]);
            }
        }
    }
    // full per-pixel ss: reduce over the 4 lg4 groups (lane bits 4,5)
    #pragma unroll
    for (int ntl = 0; ntl < 2; ++ntl) {
        ssa[ntl] += __shfl_xor(ssa[ntl], 16);
        ssa[ntl] += __shfl_xor(ssa[ntl], 32);
    }

    // bias into regs: biasv[mt][r] = bias[mt*16+4lg4+r]
    f32x4 biasv[4];
    #pragma unroll
    for (int mt = 0; mt < 4; ++mt)
        biasv[mt] = *(const f32x4*)(bias + mt * 16 + 4 * lg4);

    // ---- pass-2 staging ids; issue slab-0 loads early (hide under softmax)
    const int r2 = t >> 4;                 // 0..15 (rows r2 and r2+16 per slab)
    const int pq8 = (t & 15) * 8;
    const float* xg2 = x + ximg + (size_t)r2 * 1024 + p0 + pq8;
    unsigned* const w2hi = p2hi + r2 * 68 + (pq8 >> 1);
    unsigned* const w2lo = p2lo + r2 * 68 + (pq8 >> 1);
    float4 g2[4];
    #define P2_LOAD(s_) { _Pragma("unroll")                                   \
        for (int i = 0; i < 2; ++i) {                                         \
            g2[i*2]   = *(const float4*)(xg2 + (size_t)((s_)*32 + 16*i)*1024);    \
            g2[i*2+1] = *(const float4*)(xg2 + (size_t)((s_)*32 + 16*i)*1024 + 4);\
        } }
    #define P2_WRITE(b_) { _Pragma("unroll")                                  \
        for (int i = 0; i < 2; ++i) {                                         \
            u32x4 vh, vl;                                                     \
            const u32pair ra = splitpair(g2[i*2].x,   g2[i*2].y);             \
            const u32pair rb = splitpair(g2[i*2].z,   g2[i*2].w);             \
            const u32pair rc = splitpair(g2[i*2+1].x, g2[i*2+1].y);           \
            const u32pair rd = splitpair(g2[i*2+1].z, g2[i*2+1].w);           \
            vh[0] = ra.h; vl[0] = ra.l;                                       \
            vh[1] = rb.h; vl[1] = rb.l;                                       \
            vh[2] = rc.h; vl[2] = rc.l;                                       \
            vh[3] = rd.h; vl[3] = rd.l;                                       \
            *(u32x4*)(w2hi + (b_) * 2176 + i * 1088) = vh;                    \
            *(u32x4*)(w2lo + (b_) * 2176 + i * 1088) = vl; } }
    P2_LOAD(0);

    // ---- softmax fully in-register; rn from ssa; packed a -> abuf
    #pragma unroll
    for (int ntl = 0; ntl < 2; ++ntl) {
        const int p = (2 * w + ntl) * 16 + l15;
        const float rn = 1.f / fmaxf(sqrtf(ssa[ntl]), EPSF);
        if (lg4 == 0) rn_lds[p] = rn;
        float lgv[16];
        #pragma unroll
        for (int mt = 0; mt < 4; ++mt)
            #pragma unroll
            for (int r = 0; r < 4; ++r)
                lgv[mt * 4 + r] = fmaf(acc1[mt][ntl][r], rn, biasv[mt][r]);
        float mx = lgv[0];
        #pragma unroll
        for (int i = 1; i < 16; ++i) mx = fmaxf(mx, lgv[i]);
        mx = fmaxf(mx, __shfl_xor(mx, 16));
        mx = fmaxf(mx, __shfl_xor(mx, 32));
        float den = 0.f;
        #pragma unroll
        for (int i = 0; i < 16; ++i) { lgv[i] = __expf(lgv[i] - mx); den += lgv[i]; }
        den += __shfl_xor(den, 16);
        den += __shfl_xor(den, 32);
        const float inv = 1.f / den;
        #pragma unroll
        for (int mt = 0; mt < 4; ++mt)
            #pragma unroll
            for (int r = 0; r < 4; ++r)
                abuf[(mt * 16 + 4 * lg4 + r) * 132 + p] =
                    packsplit(lgv[mt * 4 + r] * inv);
    }
    __syncthreads();                       // packed a + rn_lds visible

    // ---- A-frags for pass 2: raw a (asum) + a*rn resplit; held for all slabs
    u32x4 aphi[4], aplo[4];
    f32x4 asum_acc = f32x4{0.f, 0.f, 0.f, 0.f};
    const u32x4 ONES = {0x3F803F80u, 0x3F803F80u, 0x3F803F80u, 0x3F803F80u};
    #pragma unroll
    for (int ks = 0; ks < 4; ++ks) {
        const unsigned* ap = abuf + (k0 + l15) * 132 + ks * 32 + cs;
        const u32x4 pa = *(const u32x4*)ap;
        const u32x4 pb = *(const u32x4*)(ap + 4);
        u32x4 ahi, alo; unpack2q(pa, pb, ahi, alo);
        asum_acc = MFMA(as_bf(ahi), as_bf(ONES), asum_acc);
        asum_acc = MFMA(as_bf(alo), as_bf(ONES), asum_acc);
        // a' = a*rn, resplit once; reused by all 16 c-tiles
        const float* rp = rn_lds + ks * 32 + cs;
        const unsigned paw[8] = {pa[0],pa[1],pa[2],pa[3],pb[0],pb[1],pb[2],pb[3]};
        float av[8];
        #pragma unroll
        for (int j = 0; j < 8; ++j) {
            const float afv = __uint_as_float(paw[j] & 0xFFFF0000u)
                            + __uint_as_float(paw[j] << 16);
            av[j] = afv * rp[j];
        }
        split8v(av, aphi[ks], aplo[ks]);
    }
    __syncthreads();                       // abuf reads done -> p2 alias safe

    P2_WRITE(0);                           // slab 0

    // ================= PASS 2: agg[k][c] += a' @ x^T =================
    float* op = out + (size_t)n * 16384;
    #pragma unroll
    for (int s2 = 0; s2 < 8; ++s2) {
        if (s2 < 7) P2_LOAD(s2 + 1);
        __syncthreads();                   // slab s2 visible; dbuf safe
        const unsigned* shi = p2hi + (s2 & 1) * 2176;
        const unsigned* slo = p2lo + (s2 & 1) * 2176;
        f32x4 a2[2];
        #pragma unroll
        for (int ntl = 0; ntl < 2; ++ntl) {
            a2[ntl] = f32x4{0.f, 0.f, 0.f, 0.f};
            #pragma unroll
            for (int ks = 0; ks < 4; ++ks) {
                const int ro = (ntl * 16 + l15) * 68 + ks * 16 + lg4 * 4;
                const u32x4 xhi = *(const u32x4*)(shi + ro);
                const u32x4 xlo = *(const u32x4*)(slo + ro);
                a2[ntl] = MFMA(as_bf(aphi[ks]), as_bf(xhi), a2[ntl]);
                a2[ntl] = MFMA(as_bf(aphi[ks]), as_bf(xlo), a2[ntl]);
                a2[ntl] = MFMA(as_bf(aplo[ks]), as_bf(xhi), a2[ntl]);
            }
        }
        if (s2 < 7) P2_WRITE((s2 + 1) & 1);    // LDS write before atomics
        #pragma unroll
        for (int ntl = 0; ntl < 2; ++ntl) {
            const int c = s2 * 32 + ntl * 16 + l15;
            #pragma unroll
            for (int r = 0; r < 4; ++r)
                atomicAdd(&op[(k0 + lg4 * 4 + r) * 256 + c], a2[ntl][r]);
        }
    }
    if (l15 == 0) {
        #pragma unroll
        for (int r = 0; r < 4; ++r)
            atomicAdd(&asum_g[n * 64 + k0 + lg4 * 4 + r], asum_acc[r]);
    }
}

__global__ __launch_bounds__(256) void netvlad_epi(
    float* __restrict__ out, const float* __restrict__ asum_g,
    const float* __restrict__ cent) {
    __shared__ float wred[4];
    __shared__ float gs_sh;
    const int n = blockIdx.x;
    const int t = threadIdx.x;
    const int k = t >> 2;          // 4 threads per cluster row
    const int q = t & 3;
    float* op = out + (size_t)n * 16384 + k * 256 + q * 64;
    const float* cp = cent + k * 256 + q * 64;
    const float as = asum_g[n * 64 + k];

    float v[64];
    float ss = 0.f;
    #pragma unroll
    for (int i = 0; i < 64; i += 4) {
        const float4 av = *(const float4*)&op[i];
        const float4 cv = *(const float4*)&cp[i];
        v[i+0] = fmaf(-as, cv.x, av.x);
        v[i+1] = fmaf(-as, cv.y, av.y);
        v[i+2] = fmaf(-as, cv.z, av.z);
        v[i+3] = fmaf(-as, cv.w, av.w);
        ss = fmaf(v[i+0], v[i+0], ss);
        ss = fmaf(v[i+1], v[i+1], ss);
        ss = fmaf(v[i+2], v[i+2], ss);
        ss = fmaf(v[i+3], v[i+3], ss);
    }
    ss += __shfl_xor(ss, 1);
    ss += __shfl_xor(ss, 2);
    const float iscale = 1.f / fmaxf(sqrtf(ss), EPSF);

    float gsum = (q == 0) ? ss * iscale * iscale : 0.f;
    #pragma unroll
    for (int off = 4; off < 64; off <<= 1) gsum += __shfl_xor(gsum, off);
    if ((t & 63) == 0) wred[t >> 6] = gsum;
    __syncthreads();
    if (t == 0) {
        const float tot = wred[0] + wred[1] + wred[2] + wred[3];
        gs_sh = 1.f / fmaxf(sqrtf(tot), EPSF);
    }
    __syncthreads();
    const float fs = iscale * gs_sh;
    #pragma unroll
    for (int i = 0; i < 64; i += 4) {
        float4 w4;
        w4.x = v[i+0] * fs; w4.y = v[i+1] * fs;
        w4.z = v[i+2] * fs; w4.w = v[i+3] * fs;
        *(float4*)&op[i] = w4;
    }
}

extern "C" void kernel_launch(void* const* d_in, const int* in_sizes, int n_in,
                              void* d_out, int out_size, void* d_ws, size_t ws_size,
                              hipStream_t stream) {
    (void)in_sizes; (void)n_in; (void)ws_size;
    const float* x    = (const float*)d_in[0];
    const float* wmat = (const float*)d_in[1];
    const float* b    = (const float*)d_in[2];
    const float* cent = (const float*)d_in[3];
    float* out = (float*)d_out;
    unsigned* whiG = (unsigned*)d_ws;              // 8192 u32
    unsigned* wloG = whiG + 8192;                  // 8192 u32
    float* asum_g  = (float*)(whiG + 16384);       // 8192 f32

    hipMemsetAsync(d_out, 0, (size_t)out_size * sizeof(float), stream);
    hipMemsetAsync(asum_g, 0, 128 * 64 * sizeof(float), stream);
    split_w_kernel<<<8, 256, 0, stream>>>(wmat, whiG, wloG);
    netvlad_mfma<<<1024, 256, 0, stream>>>(x, whiG, wloG, b, out, asum_g);
    netvlad_epi<<<128, 256, 0, stream>>>(out, asum_g, cent);
}